// Round 1
// baseline (137.982 us; speedup 1.0000x reference)
//
#include <hip/hip_runtime.h>

// DQSN forward, fully fused.
//
// Math: out[b,o] = sum_h W2[o,h] * A[b,h] + b2[o] * (1 - 2^-16)
//   A[b,h] = sum_{t=1..16} s_t * 2^(t-17)
//   s_t from IF dynamics: v += I; s = (v >= 1); v = s ? 0 : v,  I = x[b]·W1[h] + b1[h]
// A is accumulated as an integer bitmask (exact, since weights are powers of 2).

constexpr int TSTEPS = 16;
constexpr int NB = 8;  // batch rows per block

__global__ __launch_bounds__(256) void dqsn_fwd(
    const float* __restrict__ x,
    const float* __restrict__ W1,
    const float* __restrict__ b1,
    const float* __restrict__ W2,
    const float* __restrict__ b2,
    float* __restrict__ out,
    int B, int H)
{
    const int tid = threadIdx.x;
    const int b0  = blockIdx.x * NB;

    // x rows for this block: wave-uniform -> compiler places in SGPRs (s_load)
    float xs0[NB], xs1[NB], xs2[NB], xs3[NB];
#pragma unroll
    for (int i = 0; i < NB; ++i) {
        const int bi = (b0 + i < B) ? (b0 + i) : (B - 1);
        xs0[i] = x[bi * 4 + 0];
        xs1[i] = x[bi * 4 + 1];
        xs2[i] = x[bi * 4 + 2];
        xs3[i] = x[bi * 4 + 3];
    }

    float acc0[NB], acc1[NB];
#pragma unroll
    for (int i = 0; i < NB; ++i) { acc0[i] = 0.0f; acc1[i] = 0.0f; }

    for (int h = tid; h < H; h += 256) {
        const float4 w1 = *reinterpret_cast<const float4*>(W1 + (size_t)h * 4);
        const float bb  = b1[h];
        const float w2a = W2[h];
        const float w2b = W2[H + h];

#pragma unroll
        for (int i = 0; i < NB; ++i) {
            const float I = fmaf(xs0[i], w1.x,
                            fmaf(xs1[i], w1.y,
                            fmaf(xs2[i], w1.z,
                            fmaf(xs3[i], w1.w, bb))));
            // IF neuron: exact fp32 replication of reference step sequence
            float v = 0.0f;
            unsigned m = 0u;
#pragma unroll
            for (int t = 0; t < TSTEPS; ++t) {
                v += I;
                const bool s = (v >= 1.0f);
                m |= s ? (1u << t) : 0u;   // bit t  <->  weight 2^(t-16)
                v = s ? 0.0f : v;
            }
            const float A = (float)m * 0x1p-16f;  // exact: m < 2^17
            acc0[i] = fmaf(A, w2a, acc0[i]);
            acc1[i] = fmaf(A, w2b, acc1[i]);
        }
    }

    // ---- reduce partial sums across the 256 threads ----
    // wave-level butterfly (64 lanes)
#pragma unroll
    for (int i = 0; i < NB; ++i) {
#pragma unroll
        for (int off = 32; off > 0; off >>= 1) {
            acc0[i] += __shfl_xor(acc0[i], off, 64);
            acc1[i] += __shfl_xor(acc1[i], off, 64);
        }
    }

    __shared__ float red[4][NB][2];
    const int wave = tid >> 6;
    if ((tid & 63) == 0) {
#pragma unroll
        for (int i = 0; i < NB; ++i) {
            red[wave][i][0] = acc0[i];
            red[wave][i][1] = acc1[i];
        }
    }
    __syncthreads();

    if (tid < NB * 2) {
        const int i = tid >> 1;
        const int o = tid & 1;
        if (b0 + i < B) {
            const float s = ((red[0][i][o] + red[1][i][o]) +
                             (red[2][i][o] + red[3][i][o]))
                          + b2[o] * (1.0f - 0x1p-16f);
            out[(b0 + i) * 2 + o] = s;
        }
    }
}

extern "C" void kernel_launch(void* const* d_in, const int* in_sizes, int n_in,
                              void* d_out, int out_size, void* d_ws, size_t ws_size,
                              hipStream_t stream) {
    const float* x  = (const float*)d_in[0];
    const float* W1 = (const float*)d_in[1];
    const float* b1 = (const float*)d_in[2];
    const float* W2 = (const float*)d_in[3];
    const float* b2 = (const float*)d_in[4];
    float* out = (float*)d_out;

    const int B = in_sizes[0] / 4;   // 16384
    const int H = in_sizes[2];       // 4096

    const int grid = (B + NB - 1) / NB;
    dqsn_fwd<<<grid, 256, 0, stream>>>(x, W1, b1, W2, b2, out, B, H);
}

// Round 2
// 88.870 us; speedup vs baseline: 1.5526x; 1.5526x over previous
//
#include <hip/hip_runtime.h>

// DQSN forward, fully fused, exact-periodicity formulation.
//
// out[b,o] = sum_h W2[o,h] * A[b,h] + b2[o] * (1 - 2^-16)
// A[b,h] depends only on n = first j in 1..16 with fl-cumsum_j(I) >= 1
// (hard reset to exactly 0.0 makes the spike train exactly periodic with
//  period n, even in fp32). A(n) = sum_{k: kn<=16} 2^(kn-17), via a
//  per-lane register table + ds_bpermute.

constexpr int TSTEPS = 16;
constexpr int NB = 8;  // batch rows per block

__global__ __launch_bounds__(256) void dqsn_fwd(
    const float* __restrict__ x,
    const float* __restrict__ W1,
    const float* __restrict__ b1,
    const float* __restrict__ W2,
    const float* __restrict__ b2,
    float* __restrict__ out,
    int B, int H)
{
    const int tid  = threadIdx.x;
    const int lane = tid & 63;
    const int b0   = blockIdx.x * NB;

    // ---- per-lane A(n) table: lane l (1..16) holds A for period n=l ----
    float tval = 0.0f;
    if (lane >= 1 && lane <= TSTEPS) {
        unsigned mm = 0;
        for (int k = lane; k <= TSTEPS; k += lane) mm |= 1u << (k - 1);
        tval = (float)mm * 0x1p-16f;   // exact: mm < 2^17
    }
    const int table_reg = __float_as_int(tval);  // lanes 17..63 hold 0 -> A=0

    // x rows for this block: wave-uniform -> SGPRs
    float xs0[NB], xs1[NB], xs2[NB], xs3[NB];
#pragma unroll
    for (int i = 0; i < NB; ++i) {
        const int bi = (b0 + i < B) ? (b0 + i) : (B - 1);
        xs0[i] = x[bi * 4 + 0];
        xs1[i] = x[bi * 4 + 1];
        xs2[i] = x[bi * 4 + 2];
        xs3[i] = x[bi * 4 + 3];
    }

    float acc0[NB], acc1[NB];
#pragma unroll
    for (int i = 0; i < NB; ++i) { acc0[i] = 0.0f; acc1[i] = 0.0f; }

    for (int h = tid; h < H; h += 256) {
        const float4 w1 = *reinterpret_cast<const float4*>(W1 + (size_t)h * 4);
        const float bb  = b1[h];
        const float w2a = W2[h];
        const float w2b = W2[H + h];

        float I[NB], v[NB];
        int cnt[NB];
#pragma unroll
        for (int i = 0; i < NB; ++i) {
            I[i] = fmaf(xs0[i], w1.x,
                   fmaf(xs1[i], w1.y,
                   fmaf(xs2[i], w1.z,
                   fmaf(xs3[i], w1.w, bb))));
            v[i]   = 0.0f;
            cnt[i] = 0;
        }

        // 16 steps, 3 VALU ops each: add, cmp, carry-add.
        // cnt = #{j in 1..16 : cumsum_j < 1}  ->  n = cnt+1 (17 = never spikes)
#pragma unroll
        for (int t = 0; t < TSTEPS; ++t) {
#pragma unroll
            for (int i = 0; i < NB; ++i) {
                v[i] += I[i];
                cnt[i] += (v[i] < 1.0f) ? 1 : 0;
            }
        }

#pragma unroll
        for (int i = 0; i < NB; ++i) {
            const int idx = (cnt[i] + 1) << 2;  // lane n = cnt+1
            const float A = __int_as_float(__builtin_amdgcn_ds_bpermute(idx, table_reg));
            acc0[i] = fmaf(A, w2a, acc0[i]);
            acc1[i] = fmaf(A, w2b, acc1[i]);
        }
    }

    // ---- reduce partial sums across the 256 threads ----
#pragma unroll
    for (int i = 0; i < NB; ++i) {
#pragma unroll
        for (int off = 32; off > 0; off >>= 1) {
            acc0[i] += __shfl_xor(acc0[i], off, 64);
            acc1[i] += __shfl_xor(acc1[i], off, 64);
        }
    }

    __shared__ float red[4][NB][2];
    const int wave = tid >> 6;
    if ((tid & 63) == 0) {
#pragma unroll
        for (int i = 0; i < NB; ++i) {
            red[wave][i][0] = acc0[i];
            red[wave][i][1] = acc1[i];
        }
    }
    __syncthreads();

    if (tid < NB * 2) {
        const int i = tid >> 1;
        const int o = tid & 1;
        if (b0 + i < B) {
            const float s = ((red[0][i][o] + red[1][i][o]) +
                             (red[2][i][o] + red[3][i][o]))
                          + b2[o] * (1.0f - 0x1p-16f);
            out[(b0 + i) * 2 + o] = s;
        }
    }
}

extern "C" void kernel_launch(void* const* d_in, const int* in_sizes, int n_in,
                              void* d_out, int out_size, void* d_ws, size_t ws_size,
                              hipStream_t stream) {
    const float* x  = (const float*)d_in[0];
    const float* W1 = (const float*)d_in[1];
    const float* b1 = (const float*)d_in[2];
    const float* W2 = (const float*)d_in[3];
    const float* b2 = (const float*)d_in[4];
    float* out = (float*)d_out;

    const int B = in_sizes[0] / 4;   // 16384
    const int H = in_sizes[2];       // 4096

    const int grid = (B + NB - 1) / NB;
    dqsn_fwd<<<grid, 256, 0, stream>>>(x, W1, b1, W2, b2, out, B, H);
}

// Round 3
// 47.888 us; speedup vs baseline: 2.8814x; 1.8558x over previous
//
#include <hip/hip_runtime.h>

// DQSN forward, fully fused, closed-form spike-period solve.
//
// out[b,o] = sum_h W2[o,h] * A[b,h] + b2[o] * (1 - 2^-16)
// A[b,h] depends only on n = first j in 1..16 with fp32-cumsum_j(I) >= 1
// (hard reset to exactly 0.0 -> spike train exactly periodic with period n).
//
// n is found WITHOUT the 16-step loop: n* = min{n : n*I >= 1} in real
// arithmetic, decided exactly by sign(fma(n, I, -1)) over a 3-candidate
// window centered by v_rcp_f32. fp32-cumsum error <= ~16*2^-22, so if all
// test values are outside +-2^-17 the real crossing == fp32-cumsum crossing;
// otherwise (P ~ 2e-5) fall back to the exact 16-step simulation. Decisions
// are therefore bit-identical to the step-by-step reference dynamics.

constexpr int TSTEPS = 16;
constexpr int NB = 8;                 // batch rows per block
constexpr float TAU_BAND = 0x1p-17f;  // 7.6e-6 > cumsum error bound 3.8e-6

__global__ __launch_bounds__(256) void dqsn_fwd(
    const float* __restrict__ x,
    const float* __restrict__ W1,
    const float* __restrict__ b1,
    const float* __restrict__ W2,
    const float* __restrict__ b2,
    float* __restrict__ out,
    int B, int H)
{
    const int tid  = threadIdx.x;
    const int lane = tid & 63;
    const int b0   = blockIdx.x * NB;

    // ---- per-lane A(n) table: lane l (1..16) holds A for period n=l ----
    // lanes 0 and 17..63 hold 0.0 (covers n=17 "never spikes" and n=18 guard)
    float tval = 0.0f;
    if (lane >= 1 && lane <= TSTEPS) {
        unsigned mm = 0;
        for (int k = lane; k <= TSTEPS; k += lane) mm |= 1u << (k - 1);
        tval = (float)mm * 0x1p-16f;   // exact: mm < 2^17
    }
    const int table_reg = __float_as_int(tval);

    // x rows for this block: wave-uniform -> SGPRs
    float xs0[NB], xs1[NB], xs2[NB], xs3[NB];
#pragma unroll
    for (int i = 0; i < NB; ++i) {
        const int bi = (b0 + i < B) ? (b0 + i) : (B - 1);
        xs0[i] = x[bi * 4 + 0];
        xs1[i] = x[bi * 4 + 1];
        xs2[i] = x[bi * 4 + 2];
        xs3[i] = x[bi * 4 + 3];
    }

    float acc0[NB], acc1[NB];
#pragma unroll
    for (int i = 0; i < NB; ++i) { acc0[i] = 0.0f; acc1[i] = 0.0f; }

    for (int h = tid; h < H; h += 256) {
        const float4 w1 = *reinterpret_cast<const float4*>(W1 + (size_t)h * 4);
        const float bb  = b1[h];
        const float w2a = W2[h];
        const float w2b = W2[H + h];

#pragma unroll
        for (int i = 0; i < NB; ++i) {
            const float I = fmaf(xs0[i], w1.x,
                            fmaf(xs1[i], w1.y,
                            fmaf(xs2[i], w1.z,
                            fmaf(xs3[i], w1.w, bb))));

            // candidate window around 1/I
            const float r  = __builtin_amdgcn_rcpf(I);
            float nf = __builtin_ceilf(r);
            nf = fminf(fmaxf(nf, 1.0f), 17.0f);      // v_med3_f32
            const float nm = nf - 1.0f;
            const float np = nf + 1.0f;

            // exact real-arithmetic crossing tests: sign(fma(n,I,-1)) == sign(n*I-1)
            const float t0 = fmaf(nm, I, -1.0f);
            const float t1 = fmaf(nf, I, -1.0f);
            const float t2 = fmaf(np, I, -1.0f);

            float nsel = (t0 >= 0.0f) ? nm
                       : (t1 >= 0.0f) ? nf
                       : (t2 >= 0.0f) ? np
                       : 18.0f;                      // never spikes in window

            int idx = (int)nsel << 2;

            // band guard: if any lane's test is too close to 0, the fp32
            // cumsum could disagree with real arithmetic -> exact fallback.
            const float tmin = fminf(fminf(fabsf(t0), fabsf(t1)), fabsf(t2));
            if (__ballot(tmin < TAU_BAND)) {
                float v = 0.0f;
                int cnt = 0;
#pragma unroll
                for (int t = 0; t < TSTEPS; ++t) {
                    v += I;
                    cnt += (v < 1.0f) ? 1 : 0;
                }
                idx = (cnt + 1) << 2;                // exact for all lanes
            }

            const float A = __int_as_float(__builtin_amdgcn_ds_bpermute(idx, table_reg));
            acc0[i] = fmaf(A, w2a, acc0[i]);
            acc1[i] = fmaf(A, w2b, acc1[i]);
        }
    }

    // ---- reduce partial sums across the 256 threads ----
#pragma unroll
    for (int i = 0; i < NB; ++i) {
#pragma unroll
        for (int off = 32; off > 0; off >>= 1) {
            acc0[i] += __shfl_xor(acc0[i], off, 64);
            acc1[i] += __shfl_xor(acc1[i], off, 64);
        }
    }

    __shared__ float red[4][NB][2];
    const int wave = tid >> 6;
    if ((tid & 63) == 0) {
#pragma unroll
        for (int i = 0; i < NB; ++i) {
            red[wave][i][0] = acc0[i];
            red[wave][i][1] = acc1[i];
        }
    }
    __syncthreads();

    if (tid < NB * 2) {
        const int i = tid >> 1;
        const int o = tid & 1;
        if (b0 + i < B) {
            const float s = ((red[0][i][o] + red[1][i][o]) +
                             (red[2][i][o] + red[3][i][o]))
                          + b2[o] * (1.0f - 0x1p-16f);
            out[(b0 + i) * 2 + o] = s;
        }
    }
}

extern "C" void kernel_launch(void* const* d_in, const int* in_sizes, int n_in,
                              void* d_out, int out_size, void* d_ws, size_t ws_size,
                              hipStream_t stream) {
    const float* x  = (const float*)d_in[0];
    const float* W1 = (const float*)d_in[1];
    const float* b1 = (const float*)d_in[2];
    const float* W2 = (const float*)d_in[3];
    const float* b2 = (const float*)d_in[4];
    float* out = (float*)d_out;

    const int B = in_sizes[0] / 4;   // 16384
    const int H = in_sizes[2];       // 4096

    const int grid = (B + NB - 1) / NB;
    dqsn_fwd<<<grid, 256, 0, stream>>>(x, W1, b1, W2, b2, out, B, H);
}

// Round 4
// 43.137 us; speedup vs baseline: 3.1987x; 1.1101x over previous
//
#include <hip/hip_runtime.h>

// DQSN forward, fully fused, closed-form spike-period solve (tight form).
//
// out[b,o] = sum_h W2[o,h] * A[b,h] + b2[o] * (1 - 2^-16)
// A[b,h] depends only on n = first j in 1..16 with fp32-cumsum_j(I) >= 1
// (hard reset to exactly 0.0 -> spike train exactly periodic with period n).
//
// Classifier: r = rcp(I); m = med3(rint(r), 0, 17); d = r - m (EXACT, m=rint(r));
// n = (int)m + (d > 0). Outside |d| < 1e-4, sign(d) == sign(1/I - m) (rcp err
// ~2e-6) and the fp32-cumsum crossing == real crossing (cumsum err <= 1.6e-5),
// so n is bit-faithful to the reference dynamics. I<=0 -> m=0,d<0 -> n=0 -> A=0;
// tiny I -> n=17/18 -> A=0. In-band lanes (P~1e-4) take the exact 16-step loop.

constexpr int TSTEPS = 16;
constexpr int NB = 16;                 // batch rows per block
constexpr float GUARD = 1e-4f;

__global__ __launch_bounds__(256) void dqsn_fwd(
    const float* __restrict__ x,
    const float* __restrict__ W1,
    const float* __restrict__ b1,
    const float* __restrict__ W2,
    const float* __restrict__ b2,
    float* __restrict__ out,
    int B, int H)
{
    const int tid  = threadIdx.x;
    const int lane = tid & 63;
    const int b0   = blockIdx.x * NB;

    // per-lane A(n) table: lane l (1..16) holds A for period n=l.
    // lanes 0 and 17..63 hold 0.0 (n=0: I<=0; n=17,18: never spikes).
    float tval = 0.0f;
    if (lane >= 1 && lane <= TSTEPS) {
        unsigned mm = 0;
        for (int k = lane; k <= TSTEPS; k += lane) mm |= 1u << (k - 1);
        tval = (float)mm * 0x1p-16f;   // exact: mm < 2^17
    }
    const int table_reg = __float_as_int(tval);

    // x rows for this block: wave-uniform -> SGPRs
    float xs0[NB], xs1[NB], xs2[NB], xs3[NB];
#pragma unroll
    for (int i = 0; i < NB; ++i) {
        const int bi = (b0 + i < B) ? (b0 + i) : (B - 1);
        xs0[i] = x[bi * 4 + 0];
        xs1[i] = x[bi * 4 + 1];
        xs2[i] = x[bi * 4 + 2];
        xs3[i] = x[bi * 4 + 3];
    }

    float acc0[NB], acc1[NB];
#pragma unroll
    for (int i = 0; i < NB; ++i) { acc0[i] = 0.0f; acc1[i] = 0.0f; }

    for (int h = tid; h < H; h += 256) {
        const float4 w1 = *reinterpret_cast<const float4*>(W1 + (size_t)h * 4);
        const float bb  = b1[h];
        const float w2a = W2[h];
        const float w2b = W2[H + h];

#pragma unroll
        for (int i = 0; i < NB; ++i) {
            const float I = fmaf(xs0[i], w1.x,
                            fmaf(xs1[i], w1.y,
                            fmaf(xs2[i], w1.z,
                            fmaf(xs3[i], w1.w, bb))));

            const float r = __builtin_amdgcn_rcpf(I);
            const float m = fminf(fmaxf(__builtin_rintf(r), 0.0f), 17.0f); // v_med3
            const float d = r - m;              // exact (Sterbenz, m = rint(r))
            int n = (int)m + ((d > 0.0f) ? 1 : 0);
            int idx = n << 2;

            // guard band: decision too close to a breakpoint -> exact fallback
            if (__ballot(fabsf(d) < GUARD)) {
                float v = 0.0f;
                int cnt = 0;
#pragma unroll
                for (int t = 0; t < TSTEPS; ++t) {
                    v += I;
                    cnt += (v < 1.0f) ? 1 : 0;
                }
                idx = (cnt + 1) << 2;           // exact for all lanes
            }

            const float A = __int_as_float(__builtin_amdgcn_ds_bpermute(idx, table_reg));
            acc0[i] = fmaf(A, w2a, acc0[i]);
            acc1[i] = fmaf(A, w2b, acc1[i]);
        }
    }

    // ---- reduce partial sums across the 256 threads ----
#pragma unroll
    for (int i = 0; i < NB; ++i) {
#pragma unroll
        for (int off = 32; off > 0; off >>= 1) {
            acc0[i] += __shfl_xor(acc0[i], off, 64);
            acc1[i] += __shfl_xor(acc1[i], off, 64);
        }
    }

    __shared__ float red[4][NB][2];
    const int wave = tid >> 6;
    if ((tid & 63) == 0) {
#pragma unroll
        for (int i = 0; i < NB; ++i) {
            red[wave][i][0] = acc0[i];
            red[wave][i][1] = acc1[i];
        }
    }
    __syncthreads();

    if (tid < NB * 2) {
        const int i = tid >> 1;
        const int o = tid & 1;
        if (b0 + i < B) {
            const float s = ((red[0][i][o] + red[1][i][o]) +
                             (red[2][i][o] + red[3][i][o]))
                          + b2[o] * (1.0f - 0x1p-16f);
            out[(b0 + i) * 2 + o] = s;
        }
    }
}

extern "C" void kernel_launch(void* const* d_in, const int* in_sizes, int n_in,
                              void* d_out, int out_size, void* d_ws, size_t ws_size,
                              hipStream_t stream) {
    const float* x  = (const float*)d_in[0];
    const float* W1 = (const float*)d_in[1];
    const float* b1 = (const float*)d_in[2];
    const float* W2 = (const float*)d_in[3];
    const float* b2 = (const float*)d_in[4];
    float* out = (float*)d_out;

    const int B = in_sizes[0] / 4;   // 16384
    const int H = in_sizes[2];       // 4096

    const int grid = (B + NB - 1) / NB;
    dqsn_fwd<<<grid, 256, 0, stream>>>(x, W1, b1, W2, b2, out, B, H);
}

// Round 5
// 41.701 us; speedup vs baseline: 3.3089x; 1.0344x over previous
//
#include <hip/hip_runtime.h>

// DQSN forward, fully fused, closed-form spike-period solve + packed fp32.
//
// out[b,o] = sum_h W2[o,h] * A[b,h] + b2[o] * (1 - 2^-16)
// A[b,h] depends only on n = first j in 1..16 with fp32-cumsum_j(I) >= 1
// (hard reset to exactly 0.0 -> spike train exactly periodic with period n).
//
// Classifier: r = rcp(I); m = med3(rint(r), 0, 17); d = r - m (EXACT);
// n = (int)m + (d > 0). Outside |d| < 1e-4 the decision provably equals the
// fp32-cumsum crossing; in-band lanes (P ~ 1e-4) take the exact 16-step loop.
// I-compute and the 2-output accumulate use v_pk_fma_f32 (VOP3P) via
// ext_vector_type(2) + __builtin_elementwise_fma.

typedef float v2f __attribute__((ext_vector_type(2)));

constexpr int TSTEPS = 16;
constexpr int NB = 8;                  // batch rows per block (grid = 2048)
constexpr float GUARD = 1e-4f;

__global__ __launch_bounds__(256) void dqsn_fwd(
    const float* __restrict__ x,
    const float* __restrict__ W1,
    const float* __restrict__ b1,
    const float* __restrict__ W2,
    const float* __restrict__ b2,
    float* __restrict__ out,
    int B, int H)
{
    const int tid  = threadIdx.x;
    const int lane = tid & 63;
    const int b0   = blockIdx.x * NB;

    // per-lane A(n) table: lane l (1..16) holds A for period n=l.
    // lanes 0 and 17..63 hold 0.0 (n=0: I<=0; n=17,18: never spikes).
    float tval = 0.0f;
    if (lane >= 1 && lane <= TSTEPS) {
        unsigned mm = 0;
        for (int k = lane; k <= TSTEPS; k += lane) mm |= 1u << (k - 1);
        tval = (float)mm * 0x1p-16f;   // exact: mm < 2^17
    }
    const int table_reg = __float_as_int(tval);

    // x rows, packed as (row 2i, row 2i+1) pairs for v_pk_fma_f32
    v2f xp0[NB / 2], xp1[NB / 2], xp2[NB / 2], xp3[NB / 2];
#pragma unroll
    for (int ip = 0; ip < NB / 2; ++ip) {
        const int ba = (b0 + 2 * ip     < B) ? (b0 + 2 * ip)     : (B - 1);
        const int bb_ = (b0 + 2 * ip + 1 < B) ? (b0 + 2 * ip + 1) : (B - 1);
        xp0[ip] = (v2f){x[ba * 4 + 0], x[bb_ * 4 + 0]};
        xp1[ip] = (v2f){x[ba * 4 + 1], x[bb_ * 4 + 1]};
        xp2[ip] = (v2f){x[ba * 4 + 2], x[bb_ * 4 + 2]};
        xp3[ip] = (v2f){x[ba * 4 + 3], x[bb_ * 4 + 3]};
    }

    v2f acc[NB];   // (out0, out1) per batch row
#pragma unroll
    for (int i = 0; i < NB; ++i) acc[i] = (v2f){0.0f, 0.0f};

    for (int h = tid; h < H; h += 256) {
        const float4 w1 = *reinterpret_cast<const float4*>(W1 + (size_t)h * 4);
        const float bb  = b1[h];
        const v2f   w2  = (v2f){W2[h], W2[H + h]};

        // I for all NB rows, two at a time (v_pk_fma_f32)
        v2f I2[NB / 2];
#pragma unroll
        for (int ip = 0; ip < NB / 2; ++ip) {
            v2f t = (v2f){bb, bb};
            t = __builtin_elementwise_fma(xp3[ip], (v2f){w1.w, w1.w}, t);
            t = __builtin_elementwise_fma(xp2[ip], (v2f){w1.z, w1.z}, t);
            t = __builtin_elementwise_fma(xp1[ip], (v2f){w1.y, w1.y}, t);
            I2[ip] = __builtin_elementwise_fma(xp0[ip], (v2f){w1.x, w1.x}, t);
        }

#pragma unroll
        for (int i = 0; i < NB; ++i) {
            const float I = (i & 1) ? I2[i / 2].y : I2[i / 2].x;

            const float r = __builtin_amdgcn_rcpf(I);
            const float m = fminf(fmaxf(__builtin_rintf(r), 0.0f), 17.0f); // v_med3
            const float d = r - m;              // exact (Sterbenz, m = rint(r))
            int idx = ((int)m + ((d > 0.0f) ? 1 : 0)) << 2;

            // guard band: decision too close to a breakpoint -> exact fallback
            if (__builtin_expect((unsigned long long)__ballot(fabsf(d) < GUARD), 0)) {
                float v = 0.0f;
                int cnt = 0;
#pragma unroll
                for (int t = 0; t < TSTEPS; ++t) {
                    v += I;
                    cnt += (v < 1.0f) ? 1 : 0;
                }
                idx = (cnt + 1) << 2;           // exact for all lanes
            }

            const float A = __int_as_float(__builtin_amdgcn_ds_bpermute(idx, table_reg));
            acc[i] = __builtin_elementwise_fma((v2f){A, A}, w2, acc[i]);
        }
    }

    // ---- reduce partial sums across the 256 threads ----
#pragma unroll
    for (int i = 0; i < NB; ++i) {
#pragma unroll
        for (int off = 32; off > 0; off >>= 1) {
            acc[i].x += __shfl_xor(acc[i].x, off, 64);
            acc[i].y += __shfl_xor(acc[i].y, off, 64);
        }
    }

    __shared__ float red[4][NB][2];
    const int wave = tid >> 6;
    if ((tid & 63) == 0) {
#pragma unroll
        for (int i = 0; i < NB; ++i) {
            red[wave][i][0] = acc[i].x;
            red[wave][i][1] = acc[i].y;
        }
    }
    __syncthreads();

    if (tid < NB * 2) {
        const int i = tid >> 1;
        const int o = tid & 1;
        if (b0 + i < B) {
            const float s = ((red[0][i][o] + red[1][i][o]) +
                             (red[2][i][o] + red[3][i][o]))
                          + b2[o] * (1.0f - 0x1p-16f);
            out[(b0 + i) * 2 + o] = s;
        }
    }
}

extern "C" void kernel_launch(void* const* d_in, const int* in_sizes, int n_in,
                              void* d_out, int out_size, void* d_ws, size_t ws_size,
                              hipStream_t stream) {
    const float* x  = (const float*)d_in[0];
    const float* W1 = (const float*)d_in[1];
    const float* b1 = (const float*)d_in[2];
    const float* W2 = (const float*)d_in[3];
    const float* b2 = (const float*)d_in[4];
    float* out = (float*)d_out;

    const int B = in_sizes[0] / 4;   // 16384
    const int H = in_sizes[2];       // 4096

    const int grid = (B + NB - 1) / NB;
    dqsn_fwd<<<grid, 256, 0, stream>>>(x, W1, b1, W2, b2, out, B, H);
}

// Round 6
// 39.767 us; speedup vs baseline: 3.4698x; 1.0486x over previous
//
#include <hip/hip_runtime.h>

// DQSN forward, fully fused, closed-form spike-period solve (v3).
//
// out[b,o] = sum_h W2[o,h] * A[b,h] + b2[o] * (1 - 2^-16)
// A[b,h] depends only on n = first j in 1..16 with fp32-cumsum_j(I) >= 1
// (hard reset to exactly 0.0 -> spike train exactly periodic with period n).
//
// Classifier: r = rcp(I); n = med3(ceil(r), 0, 17); A via per-lane table +
// ds_bpermute. Exactness: for |r - nearest breakpoint| > GUARD the decision
// provably equals the fp32-cumsum crossing (rcp err <= 2e-6 abs, cumsum
// ambiguity mapped to r-space <= k*1e-6 <= 1.6e-5). ONE guard per h-iter:
// e_i = (r - ceil(r)) + 0.5 in [-0.5,0.5]; breakpoint-proximity <=> |e| near
// 0.5; max|e_i| via v_max3-with-abs chain, single ballot; fallback re-runs
// the exact 16-step simulation for all NB elements (bit-identical result).

constexpr int TSTEPS = 16;
constexpr int NB = 8;                  // batch rows per block (grid = 2048)
constexpr float GUARD = 4e-5f;

template <int CITERS>
__global__ __launch_bounds__(256) void dqsn_fwd(
    const float* __restrict__ x,
    const float* __restrict__ W1,
    const float* __restrict__ b1,
    const float* __restrict__ W2,
    const float* __restrict__ b2,
    float* __restrict__ out,
    int B, int H, int iters_rt)
{
    const int tid  = threadIdx.x;
    const int lane = tid & 63;
    const int b0   = blockIdx.x * NB;

    // per-lane A(n) table: lane l (1..16) holds A for period n=l.
    // lanes 0 and 17+ hold 0.0 (n=0: I<=0; n=17: no spike within 16 steps).
    float tval = 0.0f;
    if (lane >= 1 && lane <= TSTEPS) {
        unsigned mm = 0;
        for (int k = lane; k <= TSTEPS; k += lane) mm |= 1u << (k - 1);
        tval = (float)mm * 0x1p-16f;   // exact: mm < 2^17
    }
    const int table_reg = __float_as_int(tval);

    // x rows for this block: wave-uniform -> SGPRs
    float xs0[NB], xs1[NB], xs2[NB], xs3[NB];
#pragma unroll
    for (int i = 0; i < NB; ++i) {
        const int bi = (b0 + i < B) ? (b0 + i) : (B - 1);
        xs0[i] = x[bi * 4 + 0];
        xs1[i] = x[bi * 4 + 1];
        xs2[i] = x[bi * 4 + 2];
        xs3[i] = x[bi * 4 + 3];
    }

    float acc0[NB], acc1[NB];
#pragma unroll
    for (int i = 0; i < NB; ++i) { acc0[i] = 0.0f; acc1[i] = 0.0f; }

    const int iters = (CITERS > 0) ? CITERS : iters_rt;

#pragma unroll 4
    for (int it = 0; it < iters; ++it) {
        const int h = tid + (it << 8);
        const float4 w1 = *reinterpret_cast<const float4*>(W1 + (size_t)h * 4);
        const float bb  = b1[h];
        const float w2a = W2[h];
        const float w2b = W2[H + h];

        float I[NB];
        int   idx[NB];
        float e[NB];
#pragma unroll
        for (int i = 0; i < NB; ++i) {
            I[i] = fmaf(xs0[i], w1.x,
                   fmaf(xs1[i], w1.y,
                   fmaf(xs2[i], w1.z,
                   fmaf(xs3[i], w1.w, bb))));
            const float r = __builtin_amdgcn_rcpf(I[i]);
            const float c = __builtin_ceilf(r);
            const float m = __builtin_amdgcn_fmed3f(c, 0.0f, 17.0f);
            idx[i] = (int)m << 2;
            e[i] = (r - c) + 0.5f;     // |e| ~ 0.5  <=>  r near a breakpoint
        }

        // single guard for the whole h-iteration
        float g0 = fmaxf(fmaxf(fabsf(e[0]), fabsf(e[1])), fabsf(e[2]));
        float g1 = fmaxf(fmaxf(fabsf(e[3]), fabsf(e[4])), fabsf(e[5]));
        float g2 = fmaxf(fabsf(e[6]), fabsf(e[7]));
        const float gmax = fmaxf(fmaxf(g0, g1), g2);

        if (__builtin_expect((unsigned long long)__ballot(gmax > 0.5f - GUARD), 0)) {
            // exact 16-step simulation for all NB elements (ground truth)
#pragma unroll
            for (int i = 0; i < NB; ++i) {
                float v = 0.0f;
                int cnt = 0;
#pragma unroll
                for (int t = 0; t < TSTEPS; ++t) {
                    v += I[i];
                    cnt += (v < 1.0f) ? 1 : 0;
                }
                idx[i] = (cnt + 1 <= 16 ? cnt + 1 : 17) << 2;
            }
        }

#pragma unroll
        for (int i = 0; i < NB; ++i) {
            const float A = __int_as_float(__builtin_amdgcn_ds_bpermute(idx[i], table_reg));
            acc0[i] = fmaf(A, w2a, acc0[i]);
            acc1[i] = fmaf(A, w2b, acc1[i]);
        }
    }

    // ---- reduce partial sums across the 256 threads ----
#pragma unroll
    for (int i = 0; i < NB; ++i) {
#pragma unroll
        for (int off = 32; off > 0; off >>= 1) {
            acc0[i] += __shfl_xor(acc0[i], off, 64);
            acc1[i] += __shfl_xor(acc1[i], off, 64);
        }
    }

    __shared__ float red[4][NB][2];
    const int wave = tid >> 6;
    if ((tid & 63) == 0) {
#pragma unroll
        for (int i = 0; i < NB; ++i) {
            red[wave][i][0] = acc0[i];
            red[wave][i][1] = acc1[i];
        }
    }
    __syncthreads();

    if (tid < NB * 2) {
        const int i = tid >> 1;
        const int o = tid & 1;
        if (b0 + i < B) {
            const float s = ((red[0][i][o] + red[1][i][o]) +
                             (red[2][i][o] + red[3][i][o]))
                          + b2[o] * (1.0f - 0x1p-16f);
            out[(b0 + i) * 2 + o] = s;
        }
    }
}

extern "C" void kernel_launch(void* const* d_in, const int* in_sizes, int n_in,
                              void* d_out, int out_size, void* d_ws, size_t ws_size,
                              hipStream_t stream) {
    const float* x  = (const float*)d_in[0];
    const float* W1 = (const float*)d_in[1];
    const float* b1 = (const float*)d_in[2];
    const float* W2 = (const float*)d_in[3];
    const float* b2 = (const float*)d_in[4];
    float* out = (float*)d_out;

    const int B = in_sizes[0] / 4;   // 16384
    const int H = in_sizes[2];       // 4096

    const int grid = (B + NB - 1) / NB;
    if (H == 4096) {
        dqsn_fwd<16><<<grid, 256, 0, stream>>>(x, W1, b1, W2, b2, out, B, H, 16);
    } else {
        dqsn_fwd<0><<<grid, 256, 0, stream>>>(x, W1, b1, W2, b2, out, B, H, H / 256);
    }
}

// Round 7
// 39.151 us; speedup vs baseline: 3.5244x; 1.0157x over previous
//
#include <hip/hip_runtime.h>

// DQSN forward, fully fused, closed-form spike-period solve (v4).
//
// out[b,o] = sum_h W2[o,h] * A[b,h] + b2[o] * (1 - 2^-16)
// A[b,h] depends only on n = first j in 1..16 with fp32-cumsum_j(I) >= 1
// (hard reset to exactly 0.0 -> spike train exactly periodic with period n).
//
// Classifier: r = rcp(I); n = med3(ceil(r), 0, 17); A via per-lane table +
// ds_bpermute. For |r - nearest breakpoint| > GUARD the decision provably
// equals the fp32-cumsum crossing (rcp err ~2e-6, cumsum ambiguity <= 1.6e-5).
// Guard is handled CORRECTIVELY: optimistic bpermute+FMA first (branchless
// main path), then a rare (P ~ 2%/wave-iter) patch-up that re-derives n via
// the exact 16-step simulation and adds (A_new - A_old)*w2.
// Loads for iteration t+1 are register-rotated at the top of iteration t.

constexpr int TSTEPS = 16;
constexpr int NB = 4;                  // batch rows per block (grid = 4096)
constexpr float GUARD = 4e-5f;

template <int CITERS>
__global__ __launch_bounds__(256) void dqsn_fwd(
    const float* __restrict__ x,
    const float* __restrict__ W1,
    const float* __restrict__ b1,
    const float* __restrict__ W2,
    const float* __restrict__ b2,
    float* __restrict__ out,
    int B, int H, int iters_rt)
{
    const int tid  = threadIdx.x;
    const int lane = tid & 63;
    const int b0   = blockIdx.x * NB;

    // per-lane A(n) table: lane l (1..16) holds A for period n=l.
    // lanes 0 and 17+ hold 0.0 (n=0: I<=0; n=17: no spike within 16 steps).
    float tval = 0.0f;
    if (lane >= 1 && lane <= TSTEPS) {
        unsigned mm = 0;
        for (int k = lane; k <= TSTEPS; k += lane) mm |= 1u << (k - 1);
        tval = (float)mm * 0x1p-16f;   // exact: mm < 2^17
    }
    const int table_reg = __float_as_int(tval);

    // x rows for this block: wave-uniform
    float xs0[NB], xs1[NB], xs2[NB], xs3[NB];
#pragma unroll
    for (int i = 0; i < NB; ++i) {
        const int bi = (b0 + i < B) ? (b0 + i) : (B - 1);
        xs0[i] = x[bi * 4 + 0];
        xs1[i] = x[bi * 4 + 1];
        xs2[i] = x[bi * 4 + 2];
        xs3[i] = x[bi * 4 + 3];
    }

    float acc0[NB], acc1[NB];
#pragma unroll
    for (int i = 0; i < NB; ++i) { acc0[i] = 0.0f; acc1[i] = 0.0f; }

    const int iters = (CITERS > 0) ? CITERS : iters_rt;

    // prologue: load iteration 0's operands
    float4 w1c = *reinterpret_cast<const float4*>(W1 + (size_t)tid * 4);
    float  bbc = b1[tid];
    float  w2ac = W2[tid];
    float  w2bc = W2[H + tid];

#pragma unroll 1
    for (int it = 0; it < iters; ++it) {
        // prefetch next iteration (scalar-uniform index; clamped for last)
        const int hn = (it + 1 < iters) ? (tid + (it + 1) * 256) : tid;
        const float4 w1n = *reinterpret_cast<const float4*>(W1 + (size_t)hn * 4);
        const float  bbn = b1[hn];
        const float  w2an = W2[hn];
        const float  w2bn = W2[H + hn];

        float I[NB];
        int   idx[NB];
        float emax = 0.0f;
#pragma unroll
        for (int i = 0; i < NB; ++i) {
            I[i] = fmaf(xs0[i], w1c.x,
                   fmaf(xs1[i], w1c.y,
                   fmaf(xs2[i], w1c.z,
                   fmaf(xs3[i], w1c.w, bbc))));
            const float r = __builtin_amdgcn_rcpf(I[i]);
            const float c = __builtin_ceilf(r);
            const float m = __builtin_amdgcn_fmed3f(c, 0.0f, 17.0f);
            idx[i] = (int)m << 2;
            emax = fmaxf(emax, fabsf((r - c) + 0.5f)); // |.|~0.5 <=> breakpoint
        }

        // optimistic lookup + accumulate (branchless main path)
#pragma unroll
        for (int i = 0; i < NB; ++i) {
            const float A = __int_as_float(__builtin_amdgcn_ds_bpermute(idx[i], table_reg));
            acc0[i] = fmaf(A, w2ac, acc0[i]);
            acc1[i] = fmaf(A, w2bc, acc1[i]);
        }

        // rare corrective patch-up: exact 16-step sim, add the delta
        if (__builtin_expect((unsigned long long)__ballot(emax > 0.5f - GUARD), 0)) {
#pragma unroll
            for (int i = 0; i < NB; ++i) {
                float v = 0.0f;
                int cnt = 0;
#pragma unroll
                for (int t = 0; t < TSTEPS; ++t) {
                    v += I[i];
                    cnt += (v < 1.0f) ? 1 : 0;
                }
                const int idx2 = (cnt + 1) << 2;     // in [1,17] -> valid lane
                const float An = __int_as_float(__builtin_amdgcn_ds_bpermute(idx2, table_reg));
                const float Ao = __int_as_float(__builtin_amdgcn_ds_bpermute(idx[i], table_reg));
                const float dA = An - Ao;
                acc0[i] = fmaf(dA, w2ac, acc0[i]);
                acc1[i] = fmaf(dA, w2bc, acc1[i]);
            }
        }

        w1c = w1n; bbc = bbn; w2ac = w2an; w2bc = w2bn;
    }

    // ---- reduce partial sums across the 256 threads ----
#pragma unroll
    for (int i = 0; i < NB; ++i) {
#pragma unroll
        for (int off = 32; off > 0; off >>= 1) {
            acc0[i] += __shfl_xor(acc0[i], off, 64);
            acc1[i] += __shfl_xor(acc1[i], off, 64);
        }
    }

    __shared__ float red[4][NB][2];
    const int wave = tid >> 6;
    if ((tid & 63) == 0) {
#pragma unroll
        for (int i = 0; i < NB; ++i) {
            red[wave][i][0] = acc0[i];
            red[wave][i][1] = acc1[i];
        }
    }
    __syncthreads();

    if (tid < NB * 2) {
        const int i = tid >> 1;
        const int o = tid & 1;
        if (b0 + i < B) {
            const float s = ((red[0][i][o] + red[1][i][o]) +
                             (red[2][i][o] + red[3][i][o]))
                          + b2[o] * (1.0f - 0x1p-16f);
            out[(b0 + i) * 2 + o] = s;
        }
    }
}

extern "C" void kernel_launch(void* const* d_in, const int* in_sizes, int n_in,
                              void* d_out, int out_size, void* d_ws, size_t ws_size,
                              hipStream_t stream) {
    const float* x  = (const float*)d_in[0];
    const float* W1 = (const float*)d_in[1];
    const float* b1 = (const float*)d_in[2];
    const float* W2 = (const float*)d_in[3];
    const float* b2 = (const float*)d_in[4];
    float* out = (float*)d_out;

    const int B = in_sizes[0] / 4;   // 16384
    const int H = in_sizes[2];       // 4096

    const int grid = (B + NB - 1) / NB;
    if (H == 4096) {
        dqsn_fwd<16><<<grid, 256, 0, stream>>>(x, W1, b1, W2, b2, out, B, H, 16);
    } else {
        dqsn_fwd<0><<<grid, 256, 0, stream>>>(x, W1, b1, W2, b2, out, B, H, H / 256);
    }
}

// Round 8
// 38.952 us; speedup vs baseline: 3.5424x; 1.0051x over previous
//
#include <hip/hip_runtime.h>

// DQSN forward, fully fused, closed-form spike-period solve (v5).
//
// out[b,o] = sum_h W2[o,h] * A[b,h] + b2[o] * (1 - 2^-16)
// A[b,h] depends only on n = first j in 1..16 with fp32-cumsum_j(I) >= 1
// (hard reset to exactly 0.0 -> spike train exactly periodic with period n).
//
// Classifier: r = rcp(I); n = med3(ceil(r), 0, 17); A via per-lane table +
// ds_bpermute. For |r - nearest integer| > GUARD the decision provably equals
// the fp32-cumsum crossing (rcp err ~2e-6, cumsum boundary shift <= 1.6e-5).
// Rare in-band cases are fixed CORRECTIVELY (exact 16-step sim, add
// (A_exact - A_opt)*w2; dA == 0.0 exactly for unaffected lanes).
//
// Pipeline: loads prefetched 2 iters ahead; classify+bpermute issued 1 iter
// ahead of consumption, so DS latency hides under the next classifier.

constexpr int TSTEPS = 16;
constexpr int NB = 8;                  // batch rows per block (grid = 2048)
constexpr float GUARD = 4e-5f;
constexpr float GTHR  = 0.5f - GUARD;

template <int CITERS>
__global__ __launch_bounds__(256) void dqsn_fwd(
    const float* __restrict__ x,
    const float* __restrict__ W1,
    const float* __restrict__ b1,
    const float* __restrict__ W2,
    const float* __restrict__ b2,
    float* __restrict__ out,
    int B, int H, int iters_rt)
{
    const int tid  = threadIdx.x;
    const int lane = tid & 63;
    const int b0   = blockIdx.x * NB;

    // per-lane A(n) table: lane l (1..16) holds A for period n=l.
    // lanes 0 and 17+ hold 0.0 (n=0: I<=0; n=17: no spike within 16 steps).
    float tval = 0.0f;
    if (lane >= 1 && lane <= TSTEPS) {
        unsigned mm = 0;
        for (int k = lane; k <= TSTEPS; k += lane) mm |= 1u << (k - 1);
        tval = (float)mm * 0x1p-16f;   // exact: mm < 2^17
    }
    const int table_reg = __float_as_int(tval);

    // x rows for this block: wave-uniform -> scalar loads / SGPRs
    float xs0[NB], xs1[NB], xs2[NB], xs3[NB];
#pragma unroll
    for (int i = 0; i < NB; ++i) {
        const int bi = (b0 + i < B) ? (b0 + i) : (B - 1);
        xs0[i] = x[bi * 4 + 0];
        xs1[i] = x[bi * 4 + 1];
        xs2[i] = x[bi * 4 + 2];
        xs3[i] = x[bi * 4 + 3];
    }

    float acc0[NB], acc1[NB];
#pragma unroll
    for (int i = 0; i < NB; ++i) { acc0[i] = 0.0f; acc1[i] = 0.0f; }

    const int iters = (CITERS > 0) ? CITERS : iters_rt;

    // ---- load stages: L(0) -> current-classify regs, L(1) -> B regs ----
    float4 w1B; float bbB, w2aB, w2bB;
    {
        const int h1 = (1 < iters) ? tid + 256 : tid;
        w1B  = *reinterpret_cast<const float4*>(W1 + (size_t)h1 * 4);
        bbB  = b1[h1];
        w2aB = W2[h1];
        w2bB = W2[H + h1];
    }

    // ---- classify + issue stage 0 ----
    float I_c[NB]; int idx_c[NB]; float A_c[NB];
    float em_c;
    float w2a_c, w2b_c;
    {
        const float4 w1 = *reinterpret_cast<const float4*>(W1 + (size_t)tid * 4);
        const float  bb = b1[tid];
        w2a_c = W2[tid];
        w2b_c = W2[H + tid];
        em_c = 0.0f;
#pragma unroll
        for (int i = 0; i < NB; ++i) {
            I_c[i] = fmaf(xs0[i], w1.x,
                     fmaf(xs1[i], w1.y,
                     fmaf(xs2[i], w1.z,
                     fmaf(xs3[i], w1.w, bb))));
            const float r = __builtin_amdgcn_rcpf(I_c[i]);
            const float c = __builtin_ceilf(r);
            idx_c[i] = (int)__builtin_amdgcn_fmed3f(c, 0.0f, 17.0f) << 2;
            em_c = fmaxf(em_c, fabsf((r - c) + 0.5f));
        }
#pragma unroll
        for (int i = 0; i < NB; ++i)
            A_c[i] = __int_as_float(__builtin_amdgcn_ds_bpermute(idx_c[i], table_reg));
    }

#pragma unroll 4
    for (int it = 0; it < iters - 1; ++it) {
        // prefetch L(it+2), clamped (harmless cached re-read on the tail)
        const int h2 = (it + 2 < iters) ? tid + (it + 2) * 256 : tid;
        const float4 w1N  = *reinterpret_cast<const float4*>(W1 + (size_t)h2 * 4);
        const float  bbN  = b1[h2];
        const float  w2aN = W2[h2];
        const float  w2bN = W2[H + h2];

        // ---- consume stage (it): A issued one full iteration ago ----
#pragma unroll
        for (int i = 0; i < NB; ++i) {
            acc0[i] = fmaf(A_c[i], w2a_c, acc0[i]);
            acc1[i] = fmaf(A_c[i], w2b_c, acc1[i]);
        }
        if (__builtin_expect((unsigned long long)__ballot(em_c > GTHR), 0)) {
#pragma unroll
            for (int i = 0; i < NB; ++i) {
                float v = 0.0f;
                int cnt = 0;
#pragma unroll
                for (int t = 0; t < TSTEPS; ++t) {
                    v += I_c[i];
                    cnt += (v < 1.0f) ? 1 : 0;
                }
                const float An = __int_as_float(
                    __builtin_amdgcn_ds_bpermute((cnt + 1) << 2, table_reg));
                const float dA = An - A_c[i];   // exactly 0.0 if unaffected
                acc0[i] = fmaf(dA, w2a_c, acc0[i]);
                acc1[i] = fmaf(dA, w2b_c, acc1[i]);
            }
        }

        // ---- classify + issue stage (it+1) from B regs ----
        em_c = 0.0f;
#pragma unroll
        for (int i = 0; i < NB; ++i) {
            I_c[i] = fmaf(xs0[i], w1B.x,
                     fmaf(xs1[i], w1B.y,
                     fmaf(xs2[i], w1B.z,
                     fmaf(xs3[i], w1B.w, bbB))));
            const float r = __builtin_amdgcn_rcpf(I_c[i]);
            const float c = __builtin_ceilf(r);
            idx_c[i] = (int)__builtin_amdgcn_fmed3f(c, 0.0f, 17.0f) << 2;
            em_c = fmaxf(em_c, fabsf((r - c) + 0.5f));
        }
#pragma unroll
        for (int i = 0; i < NB; ++i)
            A_c[i] = __int_as_float(__builtin_amdgcn_ds_bpermute(idx_c[i], table_reg));
        w2a_c = w2aB; w2b_c = w2bB;

        // rotate load stage
        w1B = w1N; bbB = bbN; w2aB = w2aN; w2bB = w2bN;
    }

    // ---- epilogue: consume the last stage ----
#pragma unroll
    for (int i = 0; i < NB; ++i) {
        acc0[i] = fmaf(A_c[i], w2a_c, acc0[i]);
        acc1[i] = fmaf(A_c[i], w2b_c, acc1[i]);
    }
    if (__builtin_expect((unsigned long long)__ballot(em_c > GTHR), 0)) {
#pragma unroll
        for (int i = 0; i < NB; ++i) {
            float v = 0.0f;
            int cnt = 0;
#pragma unroll
            for (int t = 0; t < TSTEPS; ++t) {
                v += I_c[i];
                cnt += (v < 1.0f) ? 1 : 0;
            }
            const float An = __int_as_float(
                __builtin_amdgcn_ds_bpermute((cnt + 1) << 2, table_reg));
            const float dA = An - A_c[i];
            acc0[i] = fmaf(dA, w2a_c, acc0[i]);
            acc1[i] = fmaf(dA, w2b_c, acc1[i]);
        }
    }

    // ---- reduce partial sums across the 256 threads ----
#pragma unroll
    for (int i = 0; i < NB; ++i) {
#pragma unroll
        for (int off = 32; off > 0; off >>= 1) {
            acc0[i] += __shfl_xor(acc0[i], off, 64);
            acc1[i] += __shfl_xor(acc1[i], off, 64);
        }
    }

    __shared__ float red[4][NB][2];
    const int wave = tid >> 6;
    if ((tid & 63) == 0) {
#pragma unroll
        for (int i = 0; i < NB; ++i) {
            red[wave][i][0] = acc0[i];
            red[wave][i][1] = acc1[i];
        }
    }
    __syncthreads();

    if (tid < NB * 2) {
        const int i = tid >> 1;
        const int o = tid & 1;
        if (b0 + i < B) {
            const float s = ((red[0][i][o] + red[1][i][o]) +
                             (red[2][i][o] + red[3][i][o]))
                          + b2[o] * (1.0f - 0x1p-16f);
            out[(b0 + i) * 2 + o] = s;
        }
    }
}

extern "C" void kernel_launch(void* const* d_in, const int* in_sizes, int n_in,
                              void* d_out, int out_size, void* d_ws, size_t ws_size,
                              hipStream_t stream) {
    const float* x  = (const float*)d_in[0];
    const float* W1 = (const float*)d_in[1];
    const float* b1 = (const float*)d_in[2];
    const float* W2 = (const float*)d_in[3];
    const float* b2 = (const float*)d_in[4];
    float* out = (float*)d_out;

    const int B = in_sizes[0] / 4;   // 16384
    const int H = in_sizes[2];       // 4096

    const int grid = (B + NB - 1) / NB;
    if (H == 4096) {
        dqsn_fwd<16><<<grid, 256, 0, stream>>>(x, W1, b1, W2, b2, out, B, H, 16);
    } else {
        dqsn_fwd<0><<<grid, 256, 0, stream>>>(x, W1, b1, W2, b2, out, B, H, H / 256);
    }
}